// Round 8
// baseline (298.121 us; speedup 1.0000x reference)
//
#include <hip/hip_runtime.h>
#include <math.h>

#define B_    16
#define M_    8
#define T_    250
#define L_    1024
#define NPAIR 28

#define KTOT   1024
#define XTS    516      // half2 stride per channel in sX^T (16B-aligned b128 blocks, bank-spread)

typedef _Float16 half8  __attribute__((ext_vector_type(8)));
typedef _Float16 half2t __attribute__((ext_vector_type(2)));
typedef float    floatx4 __attribute__((ext_vector_type(4)));

__device__ __align__(16) _Float16 g_Btw[64 * KTOT];

// np.triu_indices(8, k=1), extended to 32 rows (28..31 -> (0,0): harmless, never stored)
__constant__ int c_i1x[32] = {0,0,0,0,0,0,0,1,1,1,1,1,1,2,2,2,2,2,3,3,3,3,4,4,4,5,5,6, 0,0,0,0};
__constant__ int c_i2x[32] = {1,2,3,4,5,6,7,2,3,4,5,6,7,3,4,5,6,7,4,5,6,7,5,6,7,6,7,7, 0,0,0,0};

// B[n][k]: k=0 -> DC (1/1024); k=1 -> Nyquist ((-1)^n/1024); k=2b -> 2cos/1024, 2b+1 -> -2sin/1024
__global__ void init_btw() {
    int idx = blockIdx.x * 256 + threadIdx.x;
    int n = idx >> 10, k = idx & 1023;
    float v;
    if (k == 0)      v = 1.0f / 1024.0f;
    else if (k == 1) v = (n & 1) ? (-1.0f / 1024.0f) : (1.0f / 1024.0f);
    else {
        int bin = k >> 1, tau = n - 32;
        int r = (tau * bin) & 1023;
        float ang = (float)r * (6.283185307179586f / 1024.0f);
        float s, c; sincosf(ang, &s, &c);
        v = ((k & 1) ? -s : c) * (2.0f / 1024.0f);
    }
    g_Btw[idx] = (_Float16)v;
}

// Bijective XOR swizzle; verified rounds 1-7. In the FFT stages PHI(base+stride*r)
// factorizes as K(thread) ^ E(r): one v_xor per access.
#define PHI(i) ((i) ^ (((i) >> 4) & 15) ^ ((((i) >> 8) & 3) << 1))

__device__ inline float2 cmul(float2 a, float2 b) {
    return make_float2(fmaf(a.x, b.x, -a.y * b.y), fmaf(a.x, b.y, a.y * b.x));
}
__device__ inline float2 cadd(float2 a, float2 b) { return make_float2(a.x + b.x, a.y + b.y); }
__device__ inline float2 csub(float2 a, float2 b) { return make_float2(a.x - b.x, a.y - b.y); }
__device__ inline float2 cmni(float2 a) { return make_float2(a.y, -a.x); }  // a * (-i)

// DIF 8-point DFT: y_k = sum_r v_r W8^{rk}, in place
__device__ inline void dft8(float2 v[8]) {
    const float rt = 0.70710678118654752440f;
    float2 b0 = cadd(v[0], v[4]), b1 = cadd(v[1], v[5]);
    float2 b2 = cadd(v[2], v[6]), b3 = cadd(v[3], v[7]);
    float2 c0 = csub(v[0], v[4]);
    float2 t1 = csub(v[1], v[5]);
    float2 c1 = make_float2(rt * (t1.x + t1.y), rt * (t1.y - t1.x));   // *W8^1
    float2 c2 = cmni(csub(v[2], v[6]));                                 // *W8^2
    float2 t3 = csub(v[3], v[7]);
    float2 c3 = make_float2(rt * (t3.y - t3.x), -rt * (t3.x + t3.y));  // *W8^3
    float2 f0 = cadd(b0, b2), f1 = cadd(b1, b3);
    float2 g0 = csub(b0, b2), g1 = cmni(csub(b1, b3));
    v[0] = cadd(f0, f1); v[4] = csub(f0, f1);
    v[2] = cadd(g0, g1); v[6] = csub(g0, g1);
    f0 = cadd(c0, c2); f1 = cadd(c1, c3);
    g0 = csub(c0, c2); g1 = cmni(csub(c1, c3));
    v[1] = cadd(f0, f1); v[5] = csub(f0, f1);
    v[3] = cadd(g0, g1); v[7] = csub(g0, g1);
}

// twiddle powers as a depth-3 tree
__device__ inline void twiddle8(float2 v[8], float2 w1) {
    float2 w2 = cmul(w1, w1);
    float2 w3 = cmul(w2, w1);
    float2 w4 = cmul(w2, w2);
    float2 w5 = cmul(w4, w1);
    float2 w6 = cmul(w4, w2);
    float2 w7 = cmul(w4, w3);
    v[1] = cmul(v[1], w1); v[2] = cmul(v[2], w2); v[3] = cmul(v[3], w3);
    v[4] = cmul(v[4], w4); v[5] = cmul(v[5], w5); v[6] = cmul(v[6], w6);
    v[7] = cmul(v[7], w7);
}

// DIF radices (2,8,8,8): X[k] sits at p(k)
__device__ inline int posmap(int k) {
    return ((k & 1) << 9) | (((k >> 1) & 7) << 6) | (((k >> 4) & 7) << 3) | ((k >> 7) & 7);
}

// LDS: FFT workspace (32768 B) overlaps channel-major fp16 unit spectrum sX^T
// (8 ch x 516 half2 = 16512 B). Overlap is barrier-separated (read-all -> bar -> write).
union SMem {
    float2 z[4 * 1024];                  // 32768 B
    half2t X[8 * XTS];                   // 16512 B: X[ch*XTS + bin] = U_ch(bin)
};                                       // sizeof = 32768 B -> 4 blocks/CU (wave-capped)

__global__ __launch_bounds__(512, 4) void gcc_main(const float* __restrict__ x,
                                                   float* __restrict__ out) {
    __shared__ __align__(16) SMem sm;

    const int tid = threadIdx.x;
    const int t = blockIdx.x, b = blockIdx.y;
    const int f = tid & 127, c = tid >> 7;
    char* Zc = (char*)(sm.z + c * 1024);     // byte base for K^E addressing

    // per-thread base twiddle w = W_1024^f
    float ws, wc;
    sincosf((float)f * (-6.283185307179586f / 1024.0f), &ws, &wc);
    const float2 w = make_float2(wc, ws);

    // ---- fused global load + radix-2 stage (stride 512) ----
    {
        const float* xa = x + (((size_t)b * M_ + 2 * c) * T_ + t) * L_;
        const float* xb = xa + (size_t)T_ * L_;
        float va[8], vb[8];
#pragma unroll
        for (int j = 0; j < 8; ++j) { va[j] = xa[f + 128 * j]; vb[j] = xb[f + 128 * j]; }
        const int KR8 = (f ^ ((f >> 4) & 7)) * 8;
        const float rt = 0.70710678118654752440f;
#pragma unroll
        for (int q = 0; q < 4; ++q) {
            float2 a = make_float2(va[q], vb[q]);
            float2 d = make_float2(va[q + 4], vb[q + 4]);
            float2 tq = cmul(csub(a, d), w);
            float2 r;
            if (q == 0)      r = tq;                                            // *W8^0
            else if (q == 1) r = make_float2(rt * (tq.x + tq.y), rt * (tq.y - tq.x));   // *W8^1
            else if (q == 2) r = make_float2(tq.y, -tq.x);                      // *W8^2
            else             r = make_float2(rt * (tq.y - tq.x), -rt * (tq.x + tq.y)); // *W8^3
            const int E1 = ((q << 7) ^ ((q & 1) << 3) ^ ((q >> 1) << 1)) * 8;
            const int E2 = E1 ^ (512 * 8) ^ (4 * 8);
            *(float2*)(Zc + (KR8 ^ E1)) = cadd(a, d);
            *(float2*)(Zc + (KR8 ^ E2)) = r;
        }
    }
    __syncthreads();

    // ---- Stage B: radix-8, stride 64 ----
    {
        float2 wl = w;
        if (f & 64) wl = cmul(wl, make_float2(0.92387953251128674f, 0.38268343236508977f));
        const float2 wB = cmul(wl, wl);   // = W_1024^{2*(f&63)}
        const int u = f & 63, s9 = f >> 6;
        const int KB8 = (((s9 << 9) + u) ^ (u >> 4) ^ (s9 << 2)) * 8;
        float2 v[8];
#pragma unroll
        for (int r = 0; r < 8; ++r)
            v[r] = *(const float2*)(Zc + (KB8 ^ (((r << 6) | ((r & 3) << 2) | ((r >> 2) << 1)) * 8)));
        dft8(v);
        twiddle8(v, wB);
#pragma unroll
        for (int k = 0; k < 8; ++k)
            *(float2*)(Zc + (KB8 ^ (((k << 6) | ((k & 3) << 2) | ((k >> 2) << 1)) * 8))) = v[k];
    }
    __syncthreads();

    // ---- Stage C: radix-8, stride 8 ----
    {
        float s2, c2;
        sincosf((float)(f & 7) * (-6.283185307179586f / 64.0f), &s2, &c2);  // W_1024^{16*(f&7)}
        const float2 wC = make_float2(c2, s2);
        const int g = f >> 3, v3 = f & 7;
        const int KC8 = (((g << 6) + v3) ^ ((g & 3) << 2) ^ (((g >> 2) & 3) << 1)) * 8;
        float2 v[8];
#pragma unroll
        for (int r = 0; r < 8; ++r)
            v[r] = *(const float2*)(Zc + (KC8 ^ (((r << 3) | ((r >> 1) & 3)) * 8)));
        dft8(v);
        twiddle8(v, wC);
#pragma unroll
        for (int k = 0; k < 8; ++k)
            *(float2*)(Zc + (KC8 ^ (((k << 3) | ((k >> 1) & 3)) * 8))) = v[k];
    }
    __syncthreads();

    // ---- Stage D: radix-8, stride 1 ----
    {
        const int KD8 = ((f << 3) ^ ((f >> 1) & 15) ^ (((f >> 5) & 3) << 1)) * 8;
        float2 v[8];
#pragma unroll
        for (int r = 0; r < 8; ++r)
            v[r] = *(const float2*)(Zc + (KD8 ^ (r * 8)));
        dft8(v);
#pragma unroll
        for (int k = 0; k < 8; ++k)
            *(float2*)(Zc + (KD8 ^ (k * 8))) = v[k];
    }
    __syncthreads();

    // ---- One-shot unpack + per-channel PHAT normalize -> channel-major fp16 sX^T ----
    {
        const int k = tid;                       // 0..511
        const int pa = PHI(posmap(k));
        const int pb = PHI(posmap((1024 - k) & 1023));
        float2 Z8[8];
#pragma unroll
        for (int cc = 0; cc < 4; ++cc) {
            Z8[2 * cc]     = sm.z[cc * 1024 + pa];
            Z8[2 * cc + 1] = sm.z[cc * 1024 + pb];
        }
        float2 ny0 = make_float2(0.f, 0.f), ny1 = ny0, ny2 = ny0, ny3 = ny0;
        if (tid == 0) {                          // Nyquist slots, PHI(posmap(512)) == 4
            ny0 = sm.z[0 * 1024 + 4]; ny1 = sm.z[1 * 1024 + 4];
            ny2 = sm.z[2 * 1024 + 4]; ny3 = sm.z[3 * 1024 + 4];
        }
        __syncthreads();                         // ALL z reads complete

#pragma unroll
        for (int cc = 0; cc < 4; ++cc) {
            float2 Aa = Z8[2 * cc], Bb = Z8[2 * cc + 1];
            float xr = Aa.x + Bb.x, xi = Aa.y - Bb.y;    // ~2*X_{2cc} (scale dropped: PHAT)
            float yr = Aa.y + Bb.y, yi = Bb.x - Aa.x;    // ~2*X_{2cc+1}
            float mx = fmaf(xr, xr, xi * xi);
            float ix = (mx > 1e-30f) ? rsqrtf(mx) : 0.0f;
            float my = fmaf(yr, yr, yi * yi);
            float iy = (my > 1e-30f) ? rsqrtf(my) : 0.0f;
            sm.X[(2 * cc) * XTS + k]     = (half2t){(_Float16)(xr * ix), (_Float16)(xi * ix)};
            sm.X[(2 * cc + 1) * XTS + k] = (half2t){(_Float16)(yr * iy), (_Float16)(yi * iy)};
        }
        if (tid == 0) {                          // bin 512: u = sign(X) in {+1,-1,0}, imag 0
#define SGN(s_) ((_Float16)(((s_) * (s_) > 1e-30f) ? copysignf(1.0f, (s_)) : 0.0f))
            sm.X[0 * XTS + 512] = (half2t){SGN(ny0.x), (_Float16)0.f};
            sm.X[1 * XTS + 512] = (half2t){SGN(ny0.y), (_Float16)0.f};
            sm.X[2 * XTS + 512] = (half2t){SGN(ny1.x), (_Float16)0.f};
            sm.X[3 * XTS + 512] = (half2t){SGN(ny1.y), (_Float16)0.f};
            sm.X[4 * XTS + 512] = (half2t){SGN(ny2.x), (_Float16)0.f};
            sm.X[5 * XTS + 512] = (half2t){SGN(ny2.y), (_Float16)0.f};
            sm.X[6 * XTS + 512] = (half2t){SGN(ny3.x), (_Float16)0.f};
            sm.X[7 * XTS + 512] = (half2t){SGN(ny3.y), (_Float16)0.f};
#undef SGN
        }
        __syncthreads();                         // sX^T ready — LAST barrier in the kernel
    }

    // ---- Back half: BARRIER-FREE. Each lane builds its A-fragment from sX^T. ----
    // A[row][2b(+1)] = U_{i1(row)}(b) * conj(U_{i2(row)}(b)) — same f32 math, same fp16
    // rounding as the staged version -> bit-identical output. Products duplicated per
    // nt-wave (+VALU, proven free in rounds 6/7) to delete fill + A-tile + 8 barriers.
    const int lane = tid & 63, wv = tid >> 6;
    const int mt = wv >> 2, nt = wv & 3;
    const int l15 = lane & 15, quad = lane >> 4;
    const int arow = mt * 16 + l15;
    const half2t* Ua = sm.X + c_i1x[arow] * XTS;
    const half2t* Ub = sm.X + c_i2x[arow] * XTS;
    const _Float16* Bp = g_Btw + (nt * 16 + l15) * KTOT + quad * 8;
    const float nyp = (float)Ua[512][0] * (float)Ub[512][0];   // Nyquist product (col-1 hijack)
    floatx4 acc = {0.0f, 0.0f, 0.0f, 0.0f};

#pragma unroll 1
    for (int h = 0; h < 4; ++h) {
        const int hb = h * 128;
#pragma unroll
        for (int kt = 0; kt < 8; ++kt) {
            const int b0 = hb + kt * 16 + quad * 4;
            half8 ua = *(const half8*)(Ua + b0);
            half8 ub = *(const half8*)(Ub + b0);
            half8 af;
#pragma unroll
            for (int j = 0; j < 4; ++j) {
                float ar = (float)ua[2 * j], ai = (float)ua[2 * j + 1];
                float br = (float)ub[2 * j], bi = (float)ub[2 * j + 1];
                af[2 * j]     = (_Float16)fmaf(ar, br,  ai * bi);
                af[2 * j + 1] = (_Float16)fmaf(ai, br, -ar * bi);
            }
            if (kt == 0) {
                if (h == 0) af[1] = (quad == 0) ? (_Float16)nyp : af[1];
            }
            half8 bf = *(const half8*)(Bp + (h * 8 + kt) * 32);
            acc = __builtin_amdgcn_mfma_f32_16x16x32_f16(af, bf, acc, 0, 0, 0);
        }
    }

    // ---- Epilogue: C/D layout col=lane&15, row=quad*4+reg ----
#pragma unroll
    for (int r = 0; r < 4; ++r) {
        int pair = mt * 16 + quad * 4 + r;
        if (pair < NPAIR)
            out[((((size_t)b * NPAIR + pair) * T_ + t) << 6) + nt * 16 + l15] = acc[r];
    }
}

extern "C" void kernel_launch(void* const* d_in, const int* in_sizes, int n_in,
                              void* d_out, int out_size, void* d_ws, size_t ws_size,
                              hipStream_t stream) {
    (void)in_sizes; (void)n_in; (void)d_ws; (void)ws_size; (void)out_size;
    hipLaunchKernelGGL(init_btw, dim3(256), dim3(256), 0, stream);
    hipLaunchKernelGGL(gcc_main, dim3(T_, B_), dim3(512), 0, stream,
                       (const float*)d_in[0], (float*)d_out);
}